// Round 1
// baseline (559.416 us; speedup 1.0000x reference)
//
#include <hip/hip_runtime.h>
#include <hip/hip_bf16.h>
#include <math.h>

#define N_PTS 8192
#define TILE 256
#define QPB 4            // queries per block = waves per block

// F_CHAMFER*ALPHA0 = 0.02, F_CURVATURE*ALPHA0 = 0.006, F_SMOOTH*ALPHA0 = 0.01
#define W_CHAM 0.02f
#define W_CURV 0.006f
#define W_SMOO 0.01f

#define BIGF 1e30f

// ---- register-resident sorted top-K insert (static indexing only) ----
template <int K>
__device__ __forceinline__ void kinsert(float d, int idx, float (&bd)[K], int (&bi)[K]) {
    if (d < bd[K - 1]) {
        bd[K - 1] = d; bi[K - 1] = idx;
#pragma unroll
        for (int s = K - 1; s > 0; --s) {
            if (bd[s] < bd[s - 1]) {
                float td = bd[s]; bd[s] = bd[s - 1]; bd[s - 1] = td;
                int   ti = bi[s]; bi[s] = bi[s - 1]; bi[s - 1] = ti;
            }
        }
    }
}

// ---- merge 64 per-lane sorted lists into one global top-K (all lanes get result) ----
template <int K>
__device__ __forceinline__ void wave_merge(float (&bd)[K], int (&bi)[K], int lane,
                                           float (&md)[K], int (&mi)[K]) {
#pragma unroll
    for (int r = 0; r < K; ++r) {
        float bv = bd[0]; int bix = bi[0]; int bl = lane;
#pragma unroll
        for (int off = 1; off < 64; off <<= 1) {
            float ov  = __shfl_xor(bv, off);
            int   oix = __shfl_xor(bix, off);
            int   ol  = __shfl_xor(bl, off);
            if (ov < bv || (ov == bv && ol < bl)) { bv = ov; bix = oix; bl = ol; }
        }
        md[r] = bv; mi[r] = bix;
        if (lane == bl) {  // winner pops its head
#pragma unroll
            for (int t = 0; t < K - 1; ++t) { bd[t] = bd[t + 1]; bi[t] = bi[t + 1]; }
            bd[K - 1] = BIGF; bi[K - 1] = 0;
        }
    }
}

// ---- scan all N candidates (LDS-tiled) for this wave's query, keep top-K ----
template <int K>
__device__ __forceinline__ void knn_scan(const float* __restrict__ cand,
                                         float qx, float qy, float qz,
                                         float (&bd)[K], int (&bi)[K],
                                         float* sx, float* sy, float* sz,
                                         int tid, int lane) {
#pragma unroll
    for (int r = 0; r < K; ++r) { bd[r] = BIGF; bi[r] = 0; }
    for (int t = 0; t < N_PTS / TILE; ++t) {
        __syncthreads();
        const int c = t * TILE + tid;
        sx[tid] = cand[c * 3 + 0];
        sy[tid] = cand[c * 3 + 1];
        sz[tid] = cand[c * 3 + 2];
        __syncthreads();
#pragma unroll
        for (int u = 0; u < TILE / 64; ++u) {
            const int cl = u * 64 + lane;
            float dx = sx[cl] - qx, dy = sy[cl] - qy, dz = sz[cl] - qz;
            float d = dx * dx + dy * dy + dz * dz;
            kinsert<K>(d, t * TILE + cl, bd, bi);
        }
    }
}

// ---- kernel 0: pc2 = coords+gt, warp = coords+flow, zero accumulators ----
__global__ void prep_kernel(const float* __restrict__ flow, const float* __restrict__ gt,
                            const float* __restrict__ coords,
                            float* __restrict__ pc2, float* __restrict__ warp,
                            float* __restrict__ accs) {
    int i = blockIdx.x * blockDim.x + threadIdx.x;
    if (i < N_PTS * 3) {
        float c = coords[i];
        pc2[i]  = c + gt[i];
        warp[i] = c + flow[i];
    }
    if (i < 8) accs[i] = 0.0f;
}

// ---- kernel 1: curvature of pc2 via kNN(pc2,pc2,10) ----
__global__ __launch_bounds__(256) void curv2_kernel(const float* __restrict__ pc2,
                                                    float* __restrict__ curv2) {
    __shared__ float sx[TILE], sy[TILE], sz[TILE];
    const int tid = threadIdx.x, lane = tid & 63, wv = tid >> 6;
    const int q = blockIdx.x * QPB + wv;
    const float qx = pc2[q * 3 + 0], qy = pc2[q * 3 + 1], qz = pc2[q * 3 + 2];
    constexpr int K = 10;
    float bd[K]; int bi[K];
    knn_scan<K>(pc2, qx, qy, qz, bd, bi, sx, sy, sz, tid, lane);
    float md[K]; int mi[K];
    wave_merge<K>(bd, bi, lane, md, mi);
    float ax = 0.f, ay = 0.f, az = 0.f;
#pragma unroll
    for (int r = 0; r < K; ++r) {
        ax += pc2[mi[r] * 3 + 0];
        ay += pc2[mi[r] * 3 + 1];
        az += pc2[mi[r] * 3 + 2];
    }
    if (lane == 0) {
        curv2[q * 3 + 0] = (ax - 10.f * qx) * (1.f / 9.f);
        curv2[q * 3 + 1] = (ay - 10.f * qy) * (1.f / 9.f);
        curv2[q * 3 + 2] = (az - 10.f * qz) * (1.f / 9.f);
    }
}

// ---- kernel 2: kNN(pc1,pc1,10) -> moved_curv + smoothness ----
__global__ __launch_bounds__(256) void pc1_kernel(const float* __restrict__ coords,
                                                  const float* __restrict__ warp,
                                                  const float* __restrict__ flow,
                                                  const int* __restrict__ ksm_p,
                                                  float* __restrict__ mcurv,
                                                  float* __restrict__ accs) {
    __shared__ float sx[TILE], sy[TILE], sz[TILE];
    __shared__ float psm[QPB];
    const int tid = threadIdx.x, lane = tid & 63, wv = tid >> 6;
    const int q = blockIdx.x * QPB + wv;
    const float qx = coords[q * 3 + 0], qy = coords[q * 3 + 1], qz = coords[q * 3 + 2];
    constexpr int K = 10;
    float bd[K]; int bi[K];
    knn_scan<K>(coords, qx, qy, qz, bd, bi, sx, sy, sz, tid, lane);
    float md[K]; int mi[K];
    wave_merge<K>(bd, bi, lane, md, mi);

    const float wqx = warp[q * 3 + 0], wqy = warp[q * 3 + 1], wqz = warp[q * 3 + 2];
    const float fqx = flow[q * 3 + 0], fqy = flow[q * 3 + 1], fqz = flow[q * 3 + 2];
    const int ksm = ksm_p[0];  // 9
    float ax = 0.f, ay = 0.f, az = 0.f, sm = 0.f;
#pragma unroll
    for (int r = 0; r < K; ++r) {
        ax += warp[mi[r] * 3 + 0];
        ay += warp[mi[r] * 3 + 1];
        az += warp[mi[r] * 3 + 2];
        if (r < ksm) {
            float dx = flow[mi[r] * 3 + 0] - fqx;
            float dy = flow[mi[r] * 3 + 1] - fqy;
            float dz = flow[mi[r] * 3 + 2] - fqz;
            float sq = dx * dx + dy * dy + dz * dz;
            sm += (sq == 0.f) ? 0.f : sqrtf(sq);
        }
    }
    if (lane == 0) {
        mcurv[q * 3 + 0] = (ax - 10.f * wqx) * (1.f / 9.f);
        mcurv[q * 3 + 1] = (ay - 10.f * wqy) * (1.f / 9.f);
        mcurv[q * 3 + 2] = (az - 10.f * wqz) * (1.f / 9.f);
        psm[wv] = sm * 0.125f;  // /8.0 hard-coded in reference
    }
    __syncthreads();
    if (tid == 0) atomicAdd(&accs[2], psm[0] + psm[1] + psm[2] + psm[3]);
}

// ---- kernel 3: kNN(warp->pc2,5) -> chamfer dist1 + curvature-interp loss ----
__global__ __launch_bounds__(256) void cross_kernel(const float* __restrict__ warp,
                                                    const float* __restrict__ pc2,
                                                    const float* __restrict__ curv2,
                                                    const float* __restrict__ mcurv,
                                                    float* __restrict__ accs) {
    __shared__ float sx[TILE], sy[TILE], sz[TILE];
    __shared__ float pc1s[QPB], pcvs[QPB];
    const int tid = threadIdx.x, lane = tid & 63, wv = tid >> 6;
    const int q = blockIdx.x * QPB + wv;
    const float qx = warp[q * 3 + 0], qy = warp[q * 3 + 1], qz = warp[q * 3 + 2];
    constexpr int K = 5;
    float bd[K]; int bi[K];
    knn_scan<K>(pc2, qx, qy, qz, bd, bi, sx, sy, sz, tid, lane);
    float md[K]; int mi[K];
    wave_merge<K>(bd, bi, lane, md, mi);

    float w[K], wsum = 0.f;
#pragma unroll
    for (int r = 0; r < K; ++r) { w[r] = 1.f / (md[r] + 1e-8f); wsum += w[r]; }
    float ix = 0.f, iy = 0.f, iz = 0.f;
#pragma unroll
    for (int r = 0; r < K; ++r) {
        float ww = w[r] / wsum;
        ix += ww * curv2[mi[r] * 3 + 0];
        iy += ww * curv2[mi[r] * 3 + 1];
        iz += ww * curv2[mi[r] * 3 + 2];
    }
    float dx = ix - mcurv[q * 3 + 0];
    float dy = iy - mcurv[q * 3 + 1];
    float dz = iz - mcurv[q * 3 + 2];
    if (lane == 0) {
        pc1s[wv] = md[0];                       // dist1
        pcvs[wv] = dx * dx + dy * dy + dz * dz; // curvature term
    }
    __syncthreads();
    if (tid == 0) {
        atomicAdd(&accs[0], pc1s[0] + pc1s[1] + pc1s[2] + pc1s[3]);
        atomicAdd(&accs[3], pcvs[0] + pcvs[1] + pcvs[2] + pcvs[3]);
    }
}

// ---- kernel 4: reverse chamfer: min over warp for each pc2 point ----
__global__ __launch_bounds__(256) void rev_kernel(const float* __restrict__ pc2,
                                                  const float* __restrict__ warp,
                                                  float* __restrict__ accs) {
    __shared__ float sx[TILE], sy[TILE], sz[TILE];
    __shared__ float pmn[QPB];
    const int tid = threadIdx.x, lane = tid & 63, wv = tid >> 6;
    const int q = blockIdx.x * QPB + wv;
    const float qx = pc2[q * 3 + 0], qy = pc2[q * 3 + 1], qz = pc2[q * 3 + 2];
    float m = BIGF;
    for (int t = 0; t < N_PTS / TILE; ++t) {
        __syncthreads();
        const int c = t * TILE + tid;
        sx[tid] = warp[c * 3 + 0];
        sy[tid] = warp[c * 3 + 1];
        sz[tid] = warp[c * 3 + 2];
        __syncthreads();
#pragma unroll
        for (int u = 0; u < TILE / 64; ++u) {
            const int cl = u * 64 + lane;
            float dx = sx[cl] - qx, dy = sy[cl] - qy, dz = sz[cl] - qz;
            float d = dx * dx + dy * dy + dz * dz;
            m = fminf(m, d);
        }
    }
#pragma unroll
    for (int off = 1; off < 64; off <<= 1) m = fminf(m, __shfl_xor(m, off));
    if (lane == 0) pmn[wv] = m;
    __syncthreads();
    if (tid == 0) atomicAdd(&accs[1], pmn[0] + pmn[1] + pmn[2] + pmn[3]);
}

// ---- kernel 5: finalize ----
__global__ void fin_kernel(const float* __restrict__ accs, float* __restrict__ out) {
    if (threadIdx.x == 0 && blockIdx.x == 0)
        out[0] = W_CHAM * (accs[0] + accs[1]) + W_CURV * accs[3] + W_SMOO * accs[2];
}

extern "C" void kernel_launch(void* const* d_in, const int* in_sizes, int n_in,
                              void* d_out, int out_size, void* d_ws, size_t ws_size,
                              hipStream_t stream) {
    const float* flow   = (const float*)d_in[0];  // registration_pred (1,N,3)
    const float* gt     = (const float*)d_in[1];  // registration_gt   (1,N,3)
    const float* coords = (const float*)d_in[2];  // (N,3)
    const int*   ksm    = (const int*)d_in[3];    // smoothness_k (=9)

    float* ws    = (float*)d_ws;
    float* pc2   = ws;                 // 3N
    float* warp  = ws + 3 * N_PTS;     // 3N
    float* curv2 = ws + 6 * N_PTS;     // 3N
    float* mcurv = ws + 9 * N_PTS;     // 3N
    float* accs  = ws + 12 * N_PTS;    // [dist1, dist2, smooth, curv]
    float* out   = (float*)d_out;

    prep_kernel<<<(3 * N_PTS + 255) / 256, 256, 0, stream>>>(flow, gt, coords, pc2, warp, accs);
    curv2_kernel<<<N_PTS / QPB, 256, 0, stream>>>(pc2, curv2);
    pc1_kernel<<<N_PTS / QPB, 256, 0, stream>>>(coords, warp, flow, ksm, mcurv, accs);
    cross_kernel<<<N_PTS / QPB, 256, 0, stream>>>(warp, pc2, curv2, mcurv, accs);
    rev_kernel<<<N_PTS / QPB, 256, 0, stream>>>(pc2, warp, accs);
    fin_kernel<<<1, 64, 0, stream>>>(accs, out);
}